// Round 1
// baseline (338.504 us; speedup 1.0000x reference)
//
#include <hip/hip_runtime.h>
#include <math.h>

// Problem constants
#define HH 56
#define WW 56
#define NB 32
#define CC 256
#define PIX (HH*WW)            // 3136
#define M_TOT (NB*PIX)         // 100352
#define PADH 58
#define PADW 58
#define AW_STRIDE (NB*PADH*PADW)   // 107648 u64 per channel-word plane
#define T_CO 8                 // output channels per thread in bconv

// ---------------------------------------------------------------------------
// Pack weights: per output channel compute mean (double), std (ddof=1),
// sw = 2^round(log2(mean|bw|)), and sign bits packed 64/word via ballot.
// Also zero the global stat accumulators (runs before bconv every call).
// ---------------------------------------------------------------------------
__global__ __launch_bounds__(256) void pack_weights(
    const float* __restrict__ wt,
    unsigned long long* __restrict__ wbits,
    float* __restrict__ swv,
    long long* __restrict__ sumS,
    long long* __restrict__ sumSS) {
  int co = blockIdx.x;
  int t  = threadIdx.x;          // = ci
  int lane = t & 63, wid = t >> 6;

  float wv[9];
  const float* wp = wt + ((size_t)co*CC + t)*9;
  double psum = 0.0;
#pragma unroll
  for (int k = 0; k < 9; ++k) { wv[k] = wp[k]; psum += (double)wv[k]; }

  __shared__ double redm[4];
#pragma unroll
  for (int off = 32; off > 0; off >>= 1) psum += __shfl_xor(psum, off);
  if (lane == 0) redm[wid] = psum;
  __syncthreads();
  double mean = (redm[0]+redm[1]+redm[2]+redm[3]) * (1.0/2304.0);

  double pabs = 0.0, psq = 0.0;
#pragma unroll
  for (int k = 0; k < 9; ++k) {
    double d = (double)wv[k] - mean;
    pabs += fabs(d);
    psq  += d*d;
  }
#pragma unroll
  for (int off = 32; off > 0; off >>= 1) {
    pabs += __shfl_xor(pabs, off);
    psq  += __shfl_xor(psq,  off);
  }
  __shared__ double reda[4], redq[4];
  if (lane == 0) { reda[wid] = pabs; redq[wid] = psq; }
  __syncthreads();
  if (t == 0) {
    double sa = reda[0]+reda[1]+reda[2]+reda[3];
    double sq = redq[0]+redq[1]+redq[2]+redq[3];
    double stdv = sqrt(sq / 2303.0);                 // torch unbiased std
    double mabs = (sa * (1.0/2304.0)) / stdv;        // mean|bw|
    double sw = exp2(rint(log2(mabs)));              // round half-to-even
    swv[co] = (float)sw;
    sumS[co]  = 0;
    sumSS[co] = 0;
  }
  // Pack sign bits: wave wid covers ci in [64*wid, 64*wid+64) == word wid.
#pragma unroll
  for (int k = 0; k < 9; ++k) {
    unsigned long long m = __ballot(((double)wv[k] - mean) > 0.0);
    if (lane == 0) wbits[(size_t)co*36 + k*4 + wid] = m;
  }
}

// ---------------------------------------------------------------------------
// Pack activations: sign(x) -> bitmap, layout [word][n][h+1][w+1] (padded).
// Coalesced reads along pixel dim; each thread builds one 64-channel word.
// ---------------------------------------------------------------------------
__global__ __launch_bounds__(256) void pack_acts(
    const float* __restrict__ x,
    unsigned long long* __restrict__ abits) {
  int word = blockIdx.y;                       // 0..3
  int pi = blockIdx.x*256 + threadIdx.x;       // 0..100351
  int n = pi / PIX, pl = pi % PIX;
  int h = pl / WW, w = pl % WW;
  const float* xp = x + ((size_t)n*CC + (size_t)word*64)*PIX + pl;
  unsigned long long bits = 0ull;
#pragma unroll
  for (int c = 0; c < 64; ++c) {
    float v = xp[(size_t)c*PIX];
    bits |= ((unsigned long long)(v > 0.0f)) << c;
  }
  abits[(size_t)word*AW_STRIDE + ((size_t)n*PADH + (h+1))*PADW + (w+1)] = bits;
}

// ---------------------------------------------------------------------------
// Binary conv 3x3 pad 1 via XNOR-popcount. Each thread: 1 pixel x 8 co.
// s = 256*V - 2*P  (V = valid taps, P = popcount of xor over valid taps).
// Writes integer s as float into d_out; accumulates per-channel sum/sumsq
// (exact int64) for the BN batch statistics.
// ---------------------------------------------------------------------------
__global__ __launch_bounds__(256) void bconv(
    const unsigned long long* __restrict__ abits,
    const unsigned long long* __restrict__ wbits,
    float* __restrict__ out,
    unsigned long long* __restrict__ sumS,
    unsigned long long* __restrict__ sumSS) {
  __shared__ unsigned long long lw[T_CO*36];
  int cog = blockIdx.y;
  for (int i = threadIdx.x; i < T_CO*36; i += 256)
    lw[i] = wbits[(size_t)cog*T_CO*36 + i];
  __syncthreads();

  int pi = blockIdx.x*256 + threadIdx.x;
  int n = pi / PIX, pl = pi % PIX;
  int h = pl / WW, w = pl % WW;
  const unsigned long long* ab =
      abits + ((size_t)n*PADH + (h+1))*PADW + (w+1);

  int P[T_CO];
#pragma unroll
  for (int t = 0; t < T_CO; ++t) P[t] = 0;
  int V = 0;

#pragma unroll
  for (int dh = -1; dh <= 1; ++dh) {
#pragma unroll
    for (int dw = -1; dw <= 1; ++dw) {
      int tap = (dh+1)*3 + (dw+1);
      bool valid = ((unsigned)(h+dh) < HH) && ((unsigned)(w+dw) < WW);
      const unsigned long long* ap = ab + dh*PADW + dw;
      // padded bitmap: addresses always in-bounds; values masked below
      unsigned long long a0 = ap[0];
      unsigned long long a1 = ap[AW_STRIDE];
      unsigned long long a2 = ap[2*AW_STRIDE];
      unsigned long long a3 = ap[3*AW_STRIDE];
      if (valid) {
        V++;
#pragma unroll
        for (int t = 0; t < T_CO; ++t) {
          const unsigned long long* wq = &lw[t*36 + tap*4];
          P[t] += __popcll(a0 ^ wq[0]) + __popcll(a1 ^ wq[1])
                + __popcll(a2 ^ wq[2]) + __popcll(a3 ^ wq[3]);
        }
      }
    }
  }

  int lane = threadIdx.x & 63, wid = threadIdx.x >> 6;
  __shared__ long long redS[T_CO][4], redQ[T_CO][4];
#pragma unroll
  for (int t = 0; t < T_CO; ++t) {
    int s = 256*V - 2*P[t];
    int co = cog*T_CO + t;
    out[((size_t)n*CC + co)*PIX + pl] = (float)s;
    int ss = s, sq = s*s;   // |s|<=2304, wave sums fit int32
#pragma unroll
    for (int off = 32; off > 0; off >>= 1) {
      ss += __shfl_xor(ss, off);
      sq += __shfl_xor(sq, off);
    }
    if (lane == 0) { redS[t][wid] = ss; redQ[t][wid] = sq; }
  }
  __syncthreads();
  if (threadIdx.x < T_CO) {
    int t = threadIdx.x;
    long long S = redS[t][0]+redS[t][1]+redS[t][2]+redS[t][3];
    long long Q = redQ[t][0]+redQ[t][1]+redQ[t][2]+redQ[t][3];
    atomicAdd(&sumS [cog*T_CO + t], (unsigned long long)S);  // 2's-comp wrap ok
    atomicAdd(&sumSS[cog*T_CO + t], (unsigned long long)Q);
  }
}

// ---------------------------------------------------------------------------
// Per-channel BN fold: out = clip(s*A + B). y = sw*s; A = g*sw/sqrt(sw^2*var+eps)
// ---------------------------------------------------------------------------
__global__ void finalize_stats(
    const long long* __restrict__ sumS, const long long* __restrict__ sumSS,
    const float* __restrict__ swv,
    const float* __restrict__ gamma, const float* __restrict__ beta,
    float* __restrict__ AB) {
  int c = threadIdx.x;
  double mu  = (double)sumS[c]  / (double)M_TOT;
  double var = (double)sumSS[c] / (double)M_TOT - mu*mu;   // biased var of s
  double sw  = (double)swv[c];
  double inv = 1.0 / sqrt(sw*sw*var + 1e-5);
  double scale = (double)gamma[c] * sw * inv;
  double shift = (double)beta[c] - scale * mu;
  AB[c]       = (float)scale;
  AB[256 + c] = (float)shift;
}

// ---------------------------------------------------------------------------
// Apply BN + hardtanh in place over d_out (float4 vectorized).
// ---------------------------------------------------------------------------
__global__ __launch_bounds__(256) void bn_apply(
    float* __restrict__ out, const float* __restrict__ AB, int n4) {
  int i = blockIdx.x*blockDim.x + threadIdx.x;
  if (i >= n4) return;
  float4 v = ((float4*)out)[i];
  int c = ((i*4) / PIX) & (CC-1);   // 3136 % 4 == 0 -> c uniform in the float4
  float a = AB[c], b = AB[256 + c];
  v.x = fminf(1.0f, fmaxf(-1.0f, v.x*a + b));
  v.y = fminf(1.0f, fmaxf(-1.0f, v.y*a + b));
  v.z = fminf(1.0f, fmaxf(-1.0f, v.z*a + b));
  v.w = fminf(1.0f, fmaxf(-1.0f, v.w*a + b));
  ((float4*)out)[i] = v;
}

extern "C" void kernel_launch(void* const* d_in, const int* in_sizes, int n_in,
                              void* d_out, int out_size, void* d_ws, size_t ws_size,
                              hipStream_t stream) {
  (void)in_sizes; (void)n_in; (void)out_size; (void)ws_size;
  const float* x     = (const float*)d_in[0];
  const float* wt    = (const float*)d_in[1];
  const float* gamma = (const float*)d_in[2];
  const float* beta  = (const float*)d_in[3];
  float* out = (float*)d_out;

  char* ws = (char*)d_ws;
  size_t off = 0;
  unsigned long long* abits = (unsigned long long*)(ws + off);
  off += (size_t)4*AW_STRIDE*8;  off = (off + 255) & ~(size_t)255;
  unsigned long long* wbits = (unsigned long long*)(ws + off);
  off += (size_t)256*36*8;       off = (off + 255) & ~(size_t)255;
  float* swv = (float*)(ws + off); off += 256*4;
  float* AB  = (float*)(ws + off); off += 512*4;  off = (off + 255) & ~(size_t)255;
  long long* sumS  = (long long*)(ws + off); off += 256*8;
  long long* sumSS = (long long*)(ws + off); off += 256*8;

  pack_weights<<<256, 256, 0, stream>>>(wt, wbits, swv, sumS, sumSS);
  pack_acts<<<dim3(M_TOT/256, 4), 256, 0, stream>>>(x, abits);
  bconv<<<dim3(M_TOT/256, CC/T_CO), 256, 0, stream>>>(
      abits, wbits, out,
      (unsigned long long*)sumS, (unsigned long long*)sumSS);
  finalize_stats<<<1, 256, 0, stream>>>(sumS, sumSS, swv, gamma, beta, AB);
  bn_apply<<<(M_TOT*CC/4 + 255)/256, 256, 0, stream>>>(out, AB, M_TOT*CC/4);
}